// Round 16
// baseline (320.638 us; speedup 1.0000x reference)
//
#include <hip/hip_runtime.h>

typedef unsigned short u16;
typedef unsigned int   u32;

#define NIN 40

struct PtrTab { const void* p[NIN]; int n[NIN]; };
struct OffsT  { int o[38]; };
struct TOffs  { int o[14]; };
struct TOffs2 { int o[12]; };

typedef __attribute__((ext_vector_type(8))) short bf16x8;
typedef __attribute__((ext_vector_type(4))) float f32x4;
#define MFMA16(a,b,c) __builtin_amdgcn_mfma_f32_16x16x32_bf16(a,b,c,0,0,0)

__device__ __forceinline__ float bf2f(u16 u){ union{u32 i; float f;} z; z.i = ((u32)u) << 16; return z.f; }
__device__ __forceinline__ u16 f2bf(float f){ union{float f; u32 i;} z; z.f = f; u32 u = z.i; return (u16)((u + 0x7fffu + ((u >> 16) & 1u)) >> 16); }
__device__ __forceinline__ float eluf(float x){ return x > 0.f ? x : (__expf(x) - 1.f); }
__device__ __forceinline__ float sigmf(float x){ return 1.f / (1.f + __expf(-x)); }

__device__ __forceinline__ float ldv(const void* p, int i, bool BF){
  if (BF){ return bf2f(((const u16*)p)[i]); }
  return ((const float*)p)[i];
}
__device__ __forceinline__ void bf8(const u16* p, float* f){
  uint4 w = *(const uint4*)(const void*)p;
  union{u32 i; float v;} t;
  t.i = w.x << 16; f[0] = t.v;  t.i = w.x & 0xffff0000u; f[1] = t.v;
  t.i = w.y << 16; f[2] = t.v;  t.i = w.y & 0xffff0000u; f[3] = t.v;
  t.i = w.z << 16; f[4] = t.v;  t.i = w.z & 0xffff0000u; f[5] = t.v;
  t.i = w.w << 16; f[6] = t.v;  t.i = w.w & 0xffff0000u; f[7] = t.v;
}
__device__ __forceinline__ void ld8(const void* p, int i, bool BF, float* f){
  if (BF){ bf8((const u16*)p + i, f); }
  else {
    const float4* q = (const float4*)(const void*)((const float*)p + i);
    float4 a = q[0], b = q[1];
    f[0]=a.x; f[1]=a.y; f[2]=a.z; f[3]=a.w; f[4]=b.x; f[5]=b.y; f[6]=b.z; f[7]=b.w;
  }
}
__device__ __forceinline__ void st8bf(u16* p, const float* f){
  u16 tmp[8];
  #pragma unroll
  for (int jj = 0; jj < 8; ++jj) tmp[jj] = f2bf(f[jj]);
  *(uint4*)(void*)p = *(const uint4*)(const void*)tmp;
}

// ---- swizzled LDS helpers (256B row stride, byte ^= (row&7)<<4) ----
__device__ __forceinline__ void st8_swz(u16* base, int row, int k0, const float* f){
  int byte = (row*256 + k0*2) ^ ((row & 7) << 4);
  u16 tmp[8];
  #pragma unroll
  for (int jj = 0; jj < 8; ++jj) tmp[jj] = f2bf(f[jj]);
  *(uint4*)((char*)base + byte) = *(const uint4*)(const void*)tmp;
}
__device__ __forceinline__ void st1_swz(u16* base, int row, int col, float v){
  int byte = (row*256 + col*2) ^ ((row & 7) << 4);
  *(u16*)((char*)base + byte) = f2bf(v);
}
__device__ __forceinline__ bf16x8 ldfrag(const u16* base, int row, int k0){
  int byte = (row*256 + k0*2) ^ ((row & 7) << 4);
  return *(const bf16x8*)((const char*)base + byte);
}
// 512B-stride variants (K=256 tiles in k2m)
__device__ __forceinline__ bf16x8 ldfrag5(const u16* base, int row, int k0){
  int byte = (row*512 + k0*2) ^ ((row & 7) << 4);
  return *(const bf16x8*)((const char*)base + byte);
}
__device__ __forceinline__ void st1_5(u16* base, int row, int col, float v){
  int byte = (row*512 + col*2) ^ ((row & 7) << 4);
  *(u16*)((char*)base + byte) = f2bf(v);
}

// async global->LDS, 16B per lane; LDS dest = wave-uniform base + lane*16
__device__ __forceinline__ void gl16(const u16* g, u16* l){
  __builtin_amdgcn_global_load_lds((const __attribute__((address_space(1))) void*)g,
                                   (__attribute__((address_space(3))) void*)l, 16, 0, 0);
}

__device__ __forceinline__ int nbr_cnt(int n){ return n == 0 ? 4 : (n <= 8 ? 2 : 1); }
__device__ __forceinline__ int nbr_of(int n, int e){
  if (n == 0) return 1 + e;
  if (n <= 4) return e == 0 ? 0 : n + 4;
  if (n <= 8) return e == 0 ? n - 4 : n + 4;
  return n - 4;
}
__device__ __forceinline__ int prowf(int n, int r){
  return n == 0 ? 96 + r : n <= 4 ? (n-1)*8 + r : n <= 8 ? 32 + (n-5)*8 + r : 64 + (n-9)*8 + r;
}

// ---- per-input dtype probe (verified R6-R15): 1 = bf16, 0 = f32 ----
__global__ __launch_bounds__(256) void probe_kernel(PtrTab T, int* fl){
  const int i = blockIdx.x;
  __shared__ int cnt;
  if (threadIdx.x == 0) cnt = 0;
  __syncthreads();
  int S = T.n[i]; if (S > 8192) S = 8192;
  const u16* p = (const u16*)T.p[i];
  int c = 0;
  for (int w = threadIdx.x; w < S; w += 256){
    u32 e = ((u32)p[w] >> 7) & 0xFFu;
    c += (e != 0u && (e < 96u || e > 159u)) ? 1 : 0;
  }
  atomicAdd(&cnt, c);
  __syncthreads();
  if (threadIdx.x == 0) fl[i] = (cnt > (S >> 4)) ? 0 : 1;
}

__global__ __launch_bounds__(256) void convert_kernel(PtrTab T, const int* fl, u16* dst, OffsT O){
  int s = blockIdx.x + 2;
  int j = (s >= 3 && (s & 1)) ? s - 1 : s;
  bool BF = fl[j] != 0;
  const void* src = T.p[s];
  u16* d = dst + O.o[s - 2];
  int n = T.n[s];
  for (int i = blockIdx.y * 256 + threadIdx.x; i < n; i += 1024)
    d[i] = BF ? ((const u16*)src)[i] : f2bf(((const float*)src)[i]);
}

// plain transpose (k2m mats): W[k][c] -> Wt[c][k]
__global__ __launch_bounds__(256) void transpose_kernel(const u16* Wb, OffsT O, u16* Wt, TOffs TF){
  static const int srcI[14] = {2,6,10,14, 16,18,20,22, 24,26,28,30, 32,34};
  static const int KK[14]   = {128,128,128,128, 128,128,128,128, 128,128,128,128, 256,256};
  static const int NNm[14]  = {64,64,64,64, 128,128,128,128, 64,64,64,64, 256,128};
  int m = blockIdx.x;
  int K = KK[m], N = NNm[m];
  const u16* src = Wb + O.o[srcI[m]];
  u16* dst = Wt + TF.o[m];
  int tot = K * N;
  for (int i = blockIdx.y * 256 + threadIdx.x; i < tot; i += 1024){
    int k = i / N, c = i % N;
    dst[c * K + k] = src[i];
  }
}

// pre-swizzled chunk-linear weights for k1m's global_load_lds staging.
__global__ __launch_bounds__(256) void transpose2_kernel(const u16* Wb, OffsT O, u16* Wt2, TOffs2 F2){
  static const int srcI[12] = {2,6,10,14, 16,18,20,22, 24,26,28,30};
  static const int NN2[12]  = {64,64,64,64, 128,128,128,128, 64,64,64,64};
  int m = blockIdx.x;
  int N = NN2[m];
  const u16* src = Wb + O.o[srcI[m]];
  u16* dst = Wt2 + F2.o[m];
  int tot = 128 * N;
  for (int i = blockIdx.y * 256 + threadIdx.x; i < tot; i += 2048){
    int ch = i >> 11;
    int x2 = (i & 2047) * 2;
    int c  = x2 >> 8;
    int sb = x2 ^ ((c & 7) << 4);
    int scol = ch*16 + (sb >> 8);
    int sk   = (sb & 255) >> 1;
    dst[i] = src[sk * N + scol];
  }
}

// ========== K1-MFMA v5: double-buffered weight staging via LDS aliasing ==========
__global__ __launch_bounds__(512, 4) void k1m(PtrTab T, const int* flg, const u16* Wb, OffsT O,
                                              const u16* Wt2, TOffs2 F2, u16* h2g, int Btot){
  __shared__ __attribute__((aligned(16))) u16 hidB[112*128];  // hidden/h1; rows 0..63 alias wlB (phaseB, gn2)
  __shared__ __attribute__((aligned(16))) u16 xs  [112*128];  // x/h2;     rows 0..63 alias wlB (gn1)
  __shared__ __attribute__((aligned(16))) u16 wl  [4*16*128]; // weight buffer A
  __shared__ __attribute__((aligned(16))) u16 qv  [2*104*19];
  float* obs_s = (float*)qv;

  const int tid = threadIdx.x, lane = tid & 63, wid = tid >> 6;
  const int lrow = lane & 15, lkg = lane >> 4;
  const int b0 = blockIdx.x * 8;
  const bool BFobs = flg[0] != 0, BFlat = flg[1] != 0;

  // early pre-stage: phase-B chunk 0 -> wlA (flies under setup + phase A)
  {
    #pragma unroll
    for (int j = 0; j < 2; ++j){
      int u = tid + j*512, m = u >> 8, um = u & 255;
      gl16(Wt2 + F2.o[m] + um*8, wl + m*2048 + (um & 192)*8);
    }
  }
  {
    uint4 z = {0,0,0,0};
    uint4* ph = (uint4*)((char*)hidB + 104*256);
    uint4* px = (uint4*)((char*)xs   + 104*256);
    for (int u = tid; u < 128; u += 512){ ph[u] = z; px[u] = z; }
  }
  for (int u = tid; u < 8*111; u += 512){
    int r = u / 111, c = u % 111;
    int br = b0 + r; if (br >= Btot) br = Btot - 1;
    obs_s[r*111 + c] = ldv(T.p[0], br*111 + c, BFobs);
  }
  __syncthreads();

  // phase A: node-MLP hidden (elu) -> hidB at prow (type-ordered)
  for (int u = tid; u < 13*128; u += 512){
    int n = u >> 7, rem = u & 127, r = rem >> 4, h0 = (rem & 15) << 3;
    int ty  = (n == 0) ? 0 : (n <= 4) ? 1 : (n <= 8) ? 2 : 3;
    int off = (n == 0) ? 0 : (ty == 1) ? 15 + 24*(n-1)
             : (ty == 2) ? 15 + 24*(n-5) + 8 : 15 + 24*(n-9) + 16;
    int K = (n == 0) ? 15 : 8;
    const u16* w1 = Wb + O.o[4*ty];
    float acc8[8]; bf8(Wb + O.o[4*ty+1] + h0, acc8);
    for (int k = 0; k < K; ++k){
      float xv = obs_s[r*111 + off + k];
      float wf[8]; bf8(w1 + k*128 + h0, wf);
      #pragma unroll
      for (int jj = 0; jj < 8; ++jj) acc8[jj] = fmaf(xv, wf[jj], acc8[jj]);
    }
    #pragma unroll
    for (int jj = 0; jj < 8; ++jj) acc8[jj] = eluf(acc8[jj]);
    st8_swz(hidB, prowf(n, r), h0, acc8);
  }
  for (int u = tid; u < 13*64; u += 512){
    int n = u >> 6, rem = u & 63, r = rem >> 3, j0 = (rem & 7) << 3;
    int br = b0 + r; if (br >= Btot) br = Btot - 1;
    float lv[8]; ld8(T.p[1], (br*13 + n)*64 + j0, BFlat, lv);
    st8_swz(xs, n*8 + r, 64 + j0, lv);
  }
  __syncthreads();

  bf16x8 axf[4];

  // ---- phase B: x cols 0..63 = hidden @ w2[type]; wlB aliases hidB rows 0..63 ----
  if (wid < 7){
    #pragma unroll
    for (int kk = 0; kk < 4; ++kk) axf[kk] = ldfrag(hidB, wid*16 + lrow, kk*32 + lkg*8);
  }
  __syncthreads();   // axf(hidB) complete before ch1 stage clobbers hidB alias
  for (int ch = 0; ch < 4; ++ch){
    // stage next FIRST (other buffer): ch<3 -> phaseB ch+1; ch==3 -> gn1 chunk0 -> wlA
    #pragma unroll
    for (int j = 0; j < 2; ++j){
      int u = tid + j*512, m = u >> 8, um = u & 255;
      const u16* g; u16* dst;
      if (ch < 3){
        g = Wt2 + F2.o[m] + (ch+1)*2048 + um*8;
        dst = (((ch+1) & 1) ? hidB : wl) + m*2048 + (um & 192)*8;
      } else {
        g = Wt2 + F2.o[4+m] + um*8;
        dst = wl + m*2048 + (um & 192)*8;
      }
      gl16(g, dst);
    }
    const u16* wb = (ch & 1) ? hidB : wl;
    if (wid < 7){
      int t = wid;
      int tyt = t < 2 ? 1 : t < 4 ? 2 : t < 6 ? 3 : 0;
      f32x4 d = {0.f,0.f,0.f,0.f};
      #pragma unroll
      for (int kk = 0; kk < 4; ++kk){
        bf16x8 b = ldfrag(wb + tyt*2048, lrow, kk*32 + lkg*8);
        d = MFMA16(axf[kk], b, d);
      }
      int c2 = ch*16 + lrow;
      float bb = bf2f(Wb[O.o[4*tyt+3] + c2]);
      #pragma unroll
      for (int i = 0; i < 4; ++i){
        int prow = t*16 + lkg*4 + i;
        if (prow < 104){
          int n = prow < 32 ? 1 + (prow >> 3) : prow < 64 ? 5 + ((prow-32) >> 3)
                : prow < 96 ? 9 + ((prow-64) >> 3) : 0;
          st1_swz(xs, n*8 + (prow & 7), c2, d[i] + bb);
        }
      }
    }
    __syncthreads();   // drains stage; buffer rotation safe
  }

  // ---- gn1: A = x (regs); wlB aliases xs rows 0..63; h1 -> hidB ----
  if (wid < 7){
    #pragma unroll
    for (int kk = 0; kk < 4; ++kk) axf[kk] = ldfrag(xs, wid*16 + lrow, kk*32 + lkg*8);
  }
  __syncthreads();   // axf(xs) complete before ch1 stage clobbers xs alias
  {
    const u16* bk = Wb + O.o[17]; const u16* bq = Wb + O.o[19];
    const u16* bv = Wb + O.o[21]; const u16* bs = Wb + O.o[23];
    for (int ch = 0; ch < 8; ++ch){
      // stage next FIRST: ch<7 -> gn1 ch+1; ch==7 -> gn2 chunk0 -> wlA
      #pragma unroll
      for (int j = 0; j < 2; ++j){
        int u = tid + j*512, m = u >> 8, um = u & 255;
        const u16* g; u16* dst;
        if (ch < 7){
          g = Wt2 + F2.o[4+m] + (ch+1)*2048 + um*8;
          dst = (((ch+1) & 1) ? xs : wl) + m*2048 + (um & 192)*8;
        } else {
          g = Wt2 + F2.o[8+m] + um*8;
          dst = wl + m*2048 + (um & 192)*8;
        }
        gl16(g, dst);
      }
      const u16* wb = (ch & 1) ? xs : wl;
      int c0 = ch * 16;
      f32x4 kacc = {0.f,0.f,0.f,0.f}, sacc = {0.f,0.f,0.f,0.f};
      if (wid < 7){
        int t = wid;
        #pragma unroll
        for (int m = 0; m < 4; ++m){
          f32x4 d = {0.f,0.f,0.f,0.f};
          #pragma unroll
          for (int kk = 0; kk < 4; ++kk){
            bf16x8 b = ldfrag(wb + m*2048, lrow, kk*32 + lkg*8);
            d = MFMA16(axf[kk], b, d);
          }
          if (m == 0) kacc = d;
          else if (m == 3) sacc = d;
          else {
            #pragma unroll
            for (int i = 0; i < 4; ++i){
              int gr = t*16 + lkg*4 + i;
              if (gr < 104) qv[(m-1)*1976 + gr*19 + lrow] = f2bf(d[i]);
            }
          }
        }
      }
      __syncthreads();   // qv exchange + drains stage
      if (wid < 7){
        int t = wid, c = c0 + lrow;
        float bkq = bf2f(bk[c]) + bf2f(bq[c]);
        float bvv = bf2f(bv[c]);
        float bss = bf2f(bs[c]);
        #pragma unroll
        for (int i = 0; i < 4; ++i){
          int gr = t*16 + lkg*4 + i;
          if (gr < 104){
            int n = gr >> 3, rr = gr & 7;
            float acc = sacc[i] + bss;
            float kk_ = kacc[i] + bkq;
            int cnt = nbr_cnt(n);
            for (int e = 0; e < cnt; ++e){
              int s = nbr_of(n, e);
              float ql = bf2f(qv[(s*8 + rr)*19 + lrow]);
              float vl = bf2f(qv[1976 + (s*8 + rr)*19 + lrow]);
              acc += sigmf(kk_ + ql) * (vl + bvv);
            }
            st1_swz(hidB, gr, c, eluf(acc));
          }
        }
      }
      __syncthreads();   // qv reuse protection
    }
  }

  // ---- gn2: A = h1 (regs); wlB aliases hidB rows 0..63; h2 -> xs (plain) ----
  if (wid < 7){
    #pragma unroll
    for (int kk = 0; kk < 4; ++kk) axf[kk] = ldfrag(hidB, wid*16 + lrow, kk*32 + lkg*8);
  }
  __syncthreads();   // axf(h1) complete before ch1 stage clobbers hidB alias
  {
    const u16* bk = Wb + O.o[25]; const u16* bq = Wb + O.o[27];
    const u16* bv = Wb + O.o[29]; const u16* bs = Wb + O.o[31];
    for (int ch = 0; ch < 4; ++ch){
      if (ch < 3){
        #pragma unroll
        for (int j = 0; j < 2; ++j){
          int u = tid + j*512, m = u >> 8, um = u & 255;
          u16* dst = (((ch+1) & 1) ? hidB : wl) + m*2048 + (um & 192)*8;
          gl16(Wt2 + F2.o[8+m] + (ch+1)*2048 + um*8, dst);
        }
      }
      const u16* wb = (ch & 1) ? hidB : wl;
      int c0 = ch * 16;
      f32x4 kacc = {0.f,0.f,0.f,0.f}, sacc = {0.f,0.f,0.f,0.f};
      if (wid < 7){
        int t = wid;
        #pragma unroll
        for (int m = 0; m < 4; ++m){
          f32x4 d = {0.f,0.f,0.f,0.f};
          #pragma unroll
          for (int kk = 0; kk < 4; ++kk){
            bf16x8 b = ldfrag(wb + m*2048, lrow, kk*32 + lkg*8);
            d = MFMA16(axf[kk], b, d);
          }
          if (m == 0) kacc = d;
          else if (m == 3) sacc = d;
          else {
            #pragma unroll
            for (int i = 0; i < 4; ++i){
              int gr = t*16 + lkg*4 + i;
              if (gr < 104) qv[(m-1)*1976 + gr*19 + lrow] = f2bf(d[i]);
            }
          }
        }
      }
      __syncthreads();
      if (wid < 7){
        int t = wid, c = c0 + lrow;
        float bkq = bf2f(bk[c]) + bf2f(bq[c]);
        float bvv = bf2f(bv[c]);
        float bss = bf2f(bs[c]);
        #pragma unroll
        for (int i = 0; i < 4; ++i){
          int gr = t*16 + lkg*4 + i;
          if (gr < 104){
            int n = gr >> 3, rr = gr & 7;
            float acc = sacc[i] + bss;
            float kk_ = kacc[i] + bkq;
            int cnt = nbr_cnt(n);
            for (int e = 0; e < cnt; ++e){
              int s = nbr_of(n, e);
              float ql = bf2f(qv[(s*8 + rr)*19 + lrow]);
              float vl = bf2f(qv[1976 + (s*8 + rr)*19 + lrow]);
              acc += sigmf(kk_ + ql) * (vl + bvv);
            }
            xs[gr*128 + c] = f2bf(acc);
          }
        }
      }
      __syncthreads();
    }
  }

  for (int u = tid; u < 104*8; u += 512){
    int gr = u >> 3, j0 = (u & 7) << 3;
    int n = gr >> 3, rr = gr & 7;
    if (b0 + rr < Btot)
      *(uint4*)(h2g + ((b0 + rr)*13 + n)*64 + j0) = *(const uint4*)(xs + gr*128 + j0);
  }
}

// ========== K2-MFMA (proven R10): leg MLP, 64 instances/block ==========
__global__ __launch_bounds__(512) void k2m(const u16* Wb, OffsT O, const u16* Wt, TOffs TF,
                                           const u16* h2g, float* out, int Btot){
  __shared__ u16 lat [64*256];
  __shared__ u16 a1s [64*256];
  __shared__ u16 a2s [64*128];
  __shared__ u16 wbuf[2][32*256];

  const int tid  = threadIdx.x;
  const int lane = tid & 63;
  const int wid  = tid >> 6;
  const int lrow = lane & 15;
  const int lkg  = lane >> 4;
  const int r0   = blockIdx.x * 16;
  const int mt   = wid >> 1, cb = wid & 1;

  for (int u = tid; u < 64*32; u += 512){
    int inst = u >> 5, k0 = (u & 31) << 3;
    int r = inst >> 2, g = inst & 3;
    int br = r0 + r; if (br >= Btot) br = Btot - 1;
    int seg = k0 >> 6, f = k0 & 63;
    int node = (seg == 0) ? 0 : (seg - 1)*4 + 1 + g;
    uint4 v = *(const uint4*)(h2g + (br*13 + node)*64 + f);
    *(uint4*)((char*)lat + ((inst*512 + k0*2) ^ ((inst&7)<<4))) = v;
  }
  const u16* w1t = Wt + TF.o[12];
  const u16* b1  = Wb + O.o[33];
  for (int u = tid; u < 1024; u += 512){
    int c = u >> 5, kg = (u & 31) << 3;
    uint4 v = *(const uint4*)(w1t + c*256 + kg);
    *(uint4*)((char*)wbuf[0] + ((c*512 + kg*2) ^ ((c&7)<<4))) = v;
  }
  __syncthreads();

  for (int ch = 0; ch < 8; ++ch){
    if (ch < 7){
      for (int u = tid; u < 1024; u += 512){
        int c = u >> 5, kg = (u & 31) << 3;
        uint4 v = *(const uint4*)(w1t + ((ch+1)*32 + c)*256 + kg);
        *(uint4*)((char*)wbuf[(ch+1)&1] + ((c*512 + kg*2) ^ ((c&7)<<4))) = v;
      }
    }
    const u16* wb = wbuf[ch&1];
    f32x4 d = {0.f,0.f,0.f,0.f};
    #pragma unroll
    for (int kk = 0; kk < 8; ++kk){
      bf16x8 a = ldfrag5(lat, mt*16 + lrow, kk*32 + lkg*8);
      bf16x8 b = ldfrag5(wb,  cb*16 + lrow, kk*32 + lkg*8);
      d = MFMA16(a, b, d);
    }
    int col = ch*32 + cb*16 + lrow;
    float bvv = bf2f(b1[col]);
    #pragma unroll
    for (int i = 0; i < 4; ++i)
      st1_5(a1s, mt*16 + lkg*4 + i, col, eluf(d[i] + bvv));
    __syncthreads();
  }

  const u16* w2t = Wt + TF.o[13];
  const u16* b2  = Wb + O.o[35];
  for (int u = tid; u < 1024; u += 512){
    int c = u >> 5, kg = (u & 31) << 3;
    uint4 v = *(const uint4*)(w2t + c*256 + kg);
    *(uint4*)((char*)wbuf[0] + ((c*512 + kg*2) ^ ((c&7)<<4))) = v;
  }
  __syncthreads();
  for (int ch = 0; ch < 4; ++ch){
    if (ch < 3){
      for (int u = tid; u < 1024; u += 512){
        int c = u >> 5, kg = (u & 31) << 3;
        uint4 v = *(const uint4*)(w2t + ((ch+1)*32 + c)*256 + kg);
        *(uint4*)((char*)wbuf[(ch+1)&1] + ((c*512 + kg*2) ^ ((c&7)<<4))) = v;
      }
    }
    const u16* wb = wbuf[ch&1];
    f32x4 d = {0.f,0.f,0.f,0.f};
    #pragma unroll
    for (int kk = 0; kk < 8; ++kk){
      bf16x8 a = ldfrag5(a1s, mt*16 + lrow, kk*32 + lkg*8);
      bf16x8 b = ldfrag5(wb,  cb*16 + lrow, kk*32 + lkg*8);
      d = MFMA16(a, b, d);
    }
    int col = ch*32 + cb*16 + lrow;
    float bvv = bf2f(b2[col]);
    #pragma unroll
    for (int i = 0; i < 4; ++i)
      st1_swz(a2s, mt*16 + lkg*4 + i, col, eluf(d[i] + bvv));
    __syncthreads();
  }

  if (tid < 64*3){
    const u16* w3 = Wb + O.o[36], *b3 = Wb + O.o[37];
    int inst = tid / 3, c = tid % 3;
    int r = inst >> 2, g = inst & 3;
    float acc = bf2f(b3[c]);
    for (int k0 = 0; k0 < 128; k0 += 8){
      const u16* ap = (const u16*)((const char*)a2s + ((inst*256 + k0*2) ^ ((inst&7)<<4)));
      float av[8]; bf8(ap, av);
      #pragma unroll
      for (int jj = 0; jj < 8; ++jj) acc = fmaf(av[jj], bf2f(w3[(k0+jj)*3 + c]), acc);
    }
    if (r0 + r < Btot) out[(r0 + r)*12 + g*3 + c] = acc;
  }
}

// ================= fallback: R7 monolithic kernel (proven) =================
#define TPB 512
#define RR  6
__global__ __launch_bounds__(TPB) void actor_v2(PtrTab T, const int* flg, float* out, int Btot){
  __shared__ float A [RR][13][132];
  __shared__ float Bf[RR][13][132];
  __shared__ u16   Cq[3][RR][13][128];
  __shared__ float obs_s[RR][111];
  __shared__ int   fls[NIN];

  const int tid = threadIdx.x;
  const int b0  = blockIdx.x * RR;

  if (tid < NIN){ int j = (tid >= 3 && (tid & 1)) ? tid - 1 : tid; fls[tid] = flg[j]; }
  __syncthreads();
  const bool BFobs = fls[0] != 0, BFlat = fls[1] != 0;

  for (int u = tid; u < RR * 111; u += TPB){
    int r = u / 111, c = u % 111;
    int br = b0 + r; if (br >= Btot) br = Btot - 1;
    obs_s[r][c] = ldv(T.p[0], br * 111 + c, BFobs);
  }
  __syncthreads();

  for (int u = tid; u < RR * 13 * 16; u += TPB){
    int r = u / 208, rem = u % 208, n = rem >> 4, h0 = (rem & 15) << 3;
    int ty  = (n == 0) ? 0 : (n <= 4) ? 1 : (n <= 8) ? 2 : 3;
    int off = (n == 0) ? 0 : (ty == 1) ? 15 + 24 * (n - 1)
             : (ty == 2) ? 15 + 24 * (n - 5) + 8 : 15 + 24 * (n - 9) + 16;
    int K = (n == 0) ? 15 : 8;
    const void* w1 = T.p[2 + 4 * ty];
    bool bw = fls[2 + 4 * ty] != 0, bb = fls[3 + 4 * ty] != 0;
    float acc8[8]; ld8(T.p[3 + 4 * ty], h0, bb, acc8);
    for (int k = 0; k < K; ++k){
      float xv = obs_s[r][off + k];
      float wf[8]; ld8(w1, k * 128 + h0, bw, wf);
      #pragma unroll
      for (int jj = 0; jj < 8; ++jj) acc8[jj] = fmaf(xv, wf[jj], acc8[jj]);
    }
    #pragma unroll
    for (int jj = 0; jj < 8; ++jj) Bf[r][n][h0 + jj] = eluf(acc8[jj]);
  }
  __syncthreads();

  for (int u = tid; u < 13 * 8; u += TPB){
    int n = u >> 3, o0 = (u & 7) << 3;
    int ty = (n == 0) ? 0 : (n <= 4) ? 1 : (n <= 8) ? 2 : 3;
    const void* w2 = T.p[4 + 4 * ty];
    bool bw = fls[4 + 4 * ty] != 0, bb = fls[5 + 4 * ty] != 0;
    float bv[8]; ld8(T.p[5 + 4 * ty], o0, bb, bv);
    float acc[RR][8];
    #pragma unroll
    for (int r = 0; r < RR; ++r)
      #pragma unroll
      for (int jj = 0; jj < 8; ++jj) acc[r][jj] = bv[jj];
    #pragma unroll 4
    for (int k = 0; k < 128; ++k){
      float wf[8]; ld8(w2, k * 64 + o0, bw, wf);
      #pragma unroll
      for (int r = 0; r < RR; ++r){
        float xv = Bf[r][n][k];
        #pragma unroll
        for (int jj = 0; jj < 8; ++jj) acc[r][jj] = fmaf(xv, wf[jj], acc[r][jj]);
      }
    }
    #pragma unroll
    for (int r = 0; r < RR; ++r)
      #pragma unroll
      for (int jj = 0; jj < 8; ++jj) A[r][n][o0 + jj] = acc[r][jj];
  }
  for (int u = tid; u < RR * 13 * 8; u += TPB){
    int r = u / 104, rem = u % 104, n = rem >> 3, j0 = (rem & 7) << 3;
    int br = b0 + r; if (br >= Btot) br = Btot - 1;
    float lv[8]; ld8(T.p[1], (br * 13 + n) * 64 + j0, BFlat, lv);
    #pragma unroll
    for (int jj = 0; jj < 8; ++jj) A[r][n][64 + j0 + jj] = lv[jj];
  }
  __syncthreads();

  for (int u = tid; u < 4 * 13 * 16; u += TPB){
    int mat = u / 208, rem = u % 208, n = rem >> 4, j0 = (rem & 15) << 3;
    const void* W = T.p[18 + 2 * mat];
    bool bw = fls[18 + 2 * mat] != 0, bb = fls[19 + 2 * mat] != 0;
    float bv[8]; ld8(T.p[19 + 2 * mat], j0, bb, bv);
    float acc[RR][8];
    #pragma unroll
    for (int r = 0; r < RR; ++r)
      #pragma unroll
      for (int jj = 0; jj < 8; ++jj) acc[r][jj] = bv[jj];
    #pragma unroll 4
    for (int k = 0; k < 128; ++k){
      float wf[8]; ld8(W, k * 128 + j0, bw, wf);
      #pragma unroll
      for (int r = 0; r < RR; ++r){
        float xv = A[r][n][k];
        #pragma unroll
        for (int jj = 0; jj < 8; ++jj) acc[r][jj] = fmaf(xv, wf[jj], acc[r][jj]);
      }
    }
    if (mat < 3){
      #pragma unroll
      for (int r = 0; r < RR; ++r) st8bf(&Cq[mat][r][n][j0], acc[r]);
    } else {
      #pragma unroll
      for (int r = 0; r < RR; ++r)
        #pragma unroll
        for (int jj = 0; jj < 8; ++jj) Bf[r][n][j0 + jj] = acc[r][jj];
    }
  }
  __syncthreads();

  for (int u = tid; u < RR * 13 * 16; u += TPB){
    int r = u / 208, rem = u % 208, n = rem >> 4, j0 = (rem & 15) << 3;
    float acc8[8];
    #pragma unroll
    for (int jj = 0; jj < 8; ++jj) acc8[jj] = Bf[r][n][j0 + jj];
    float k8[8]; bf8(&Cq[0][r][n][j0], k8);
    int cnt = nbr_cnt(n);
    for (int e = 0; e < cnt; ++e){
      int s = nbr_of(n, e);
      float q8[8], v8[8];
      bf8(&Cq[1][r][s][j0], q8);
      bf8(&Cq[2][r][s][j0], v8);
      #pragma unroll
      for (int jj = 0; jj < 8; ++jj) acc8[jj] = fmaf(sigmf(k8[jj] + q8[jj]), v8[jj], acc8[jj]);
    }
    #pragma unroll
    for (int jj = 0; jj < 8; ++jj) Bf[r][n][j0 + jj] = eluf(acc8[jj]);
  }
  __syncthreads();

  for (int u = tid; u < 4 * 13 * 8; u += TPB){
    int mat = u / 104, rem = u % 104, n = rem >> 3, j0 = (rem & 7) << 3;
    const void* W = T.p[26 + 2 * mat];
    bool bw = fls[26 + 2 * mat] != 0, bb = fls[27 + 2 * mat] != 0;
    float bv[8]; ld8(T.p[27 + 2 * mat], j0, bb, bv);
    float acc[RR][8];
    #pragma unroll
    for (int r = 0; r < RR; ++r)
      #pragma unroll
      for (int jj = 0; jj < 8; ++jj) acc[r][jj] = bv[jj];
    #pragma unroll 4
    for (int k = 0; k < 128; ++k){
      float wf[8]; ld8(W, k * 64 + j0, bw, wf);
      #pragma unroll
      for (int r = 0; r < RR; ++r){
        float xv = Bf[r][n][k];
        #pragma unroll
        for (int jj = 0; jj < 8; ++jj) acc[r][jj] = fmaf(xv, wf[jj], acc[r][jj]);
      }
    }
    if (mat < 3){
      #pragma unroll
      for (int r = 0; r < RR; ++r) st8bf(&Cq[mat][r][n][j0], acc[r]);
    } else {
      #pragma unroll
      for (int r = 0; r < RR; ++r)
        #pragma unroll
        for (int jj = 0; jj < 8; ++jj) A[r][n][j0 + jj] = acc[r][jj];
    }
  }
  __syncthreads();

  for (int u = tid; u < RR * 13 * 8; u += TPB){
    int r = u / 104, rem = u % 104, n = rem >> 3, j0 = (rem & 7) << 3;
    float acc8[8];
    #pragma unroll
    for (int jj = 0; jj < 8; ++jj) acc8[jj] = A[r][n][j0 + jj];
    float k8[8]; bf8(&Cq[0][r][n][j0], k8);
    int cnt = nbr_cnt(n);
    for (int e = 0; e < cnt; ++e){
      int s = nbr_of(n, e);
      float q8[8], v8[8];
      bf8(&Cq[1][r][s][j0], q8);
      bf8(&Cq[2][r][s][j0], v8);
      #pragma unroll
      for (int jj = 0; jj < 8; ++jj) acc8[jj] = fmaf(sigmf(k8[jj] + q8[jj]), v8[jj], acc8[jj]);
    }
    #pragma unroll
    for (int jj = 0; jj < 8; ++jj) A[r][n][j0 + jj] = acc8[jj];
  }
  __syncthreads();

  float* a1f = (float*)&Cq[0][0][0][0];
  float* a2f = (float*)&Bf[0][0][0];
  {
    bool bw = fls[34] != 0, bb = fls[35] != 0;
    for (int u = tid; u < 6 * 32; u += TPB){
      int iq = u >> 5, j0 = (u & 31) << 3;
      float bv[8]; ld8(T.p[35], j0, bb, bv);
      float acc[4][8];
      #pragma unroll
      for (int t = 0; t < 4; ++t)
        #pragma unroll
        for (int jj = 0; jj < 8; ++jj) acc[t][jj] = bv[jj];
      #pragma unroll 2
      for (int k = 0; k < 256; ++k){
        float wf[8]; ld8(T.p[34], k * 256 + j0, bw, wf);
        int seg = k >> 6, f = k & 63;
        #pragma unroll
        for (int t = 0; t < 4; ++t){
          int inst = iq * 4 + t, r = inst >> 2, g = inst & 3;
          int node = (seg == 0) ? 0 : (seg - 1) * 4 + 1 + g;
          float xv = A[r][node][f];
          #pragma unroll
          for (int jj = 0; jj < 8; ++jj) acc[t][jj] = fmaf(xv, wf[jj], acc[t][jj]);
        }
      }
      #pragma unroll
      for (int t = 0; t < 4; ++t){
        int inst = iq * 4 + t;
        #pragma unroll
        for (int jj = 0; jj < 8; ++jj) a1f[inst * 256 + j0 + jj] = eluf(acc[t][jj]);
      }
    }
  }
  __syncthreads();
  {
    bool bw = fls[36] != 0, bb = fls[37] != 0;
    for (int u = tid; u < 6 * 16; u += TPB){
      int iq = u >> 4, j0 = (u & 15) << 3;
      float bv[8]; ld8(T.p[37], j0, bb, bv);
      float acc[4][8];
      #pragma unroll
      for (int t = 0; t < 4; ++t)
        #pragma unroll
        for (int jj = 0; jj < 8; ++jj) acc[t][jj] = bv[jj];
      #pragma unroll 2
      for (int k = 0; k < 256; ++k){
        float wf[8]; ld8(T.p[36], k * 128 + j0, bw, wf);
        #pragma unroll
        for (int t = 0; t < 4; ++t){
          float xv = a1f[(iq * 4 + t) * 256 + k];
          #pragma unroll
          for (int jj = 0; jj < 8; ++jj) acc[t][jj] = fmaf(xv, wf[jj], acc[t][jj]);
        }
      }
      #pragma unroll
      for (int t = 0; t < 4; ++t){
        int inst = iq * 4 + t;
        #pragma unroll
        for (int jj = 0; jj < 8; ++jj) a2f[inst * 128 + j0 + jj] = eluf(acc[t][jj]);
      }
    }
  }
  __syncthreads();
  if (tid < RR * 4 * 3){
    int inst = tid / 3, c = tid % 3;
    int r = inst >> 2, g = inst & 3;
    bool bw = fls[38] != 0, bb = fls[39] != 0;
    float acc = ldv(T.p[39], c, bb);
    for (int k = 0; k < 128; ++k) acc = fmaf(a2f[inst * 128 + k], ldv(T.p[38], k * 3 + c, bw), acc);
    if (b0 + r < Btot) out[(b0 + r) * 12 + g * 3 + c] = acc;
  }
}

extern "C" void kernel_launch(void* const* d_in, const int* in_sizes, int n_in,
                              void* d_out, int out_size, void* d_ws, size_t ws_size,
                              hipStream_t stream){
  (void)out_size;
  PtrTab T;
  for (int i = 0; i < NIN; ++i){
    T.p[i] = (i < n_in) ? d_in[i] : d_in[0];
    T.n[i] = (i < n_in) ? in_sizes[i] : 1;
  }
  int* fl = (int*)d_ws;
  hipLaunchKernelGGL(probe_kernel, dim3(NIN), dim3(256), 0, stream, T, fl);

  int Btot = T.n[0] / 111;

  OffsT O;
  size_t acc = 0;
  for (int s = 0; s < 38; ++s){
    O.o[s] = (int)acc;
    acc += ((size_t)T.n[s + 2] + 7) & ~(size_t)7;
  }
  static const int KK[14] = {128,128,128,128, 128,128,128,128, 128,128,128,128, 256,256};
  static const int NNm[14]= {64,64,64,64, 128,128,128,128, 64,64,64,64, 256,128};
  TOffs TF;
  int wtElems = 0;
  for (int m = 0; m < 14; ++m){ TF.o[m] = wtElems; wtElems += KK[m]*NNm[m]; }
  static const int NN2[12] = {64,64,64,64, 128,128,128,128, 64,64,64,64};
  TOffs2 F2;
  int w2Elems = 0;
  for (int m = 0; m < 12; ++m){ F2.o[m] = w2Elems; w2Elems += 128*NN2[m]; }

  size_t wtoff  = ((256 + acc * 2 + 511) / 512) * 512;
  size_t wt2off = ((wtoff + (size_t)wtElems * 2 + 511) / 512) * 512;
  size_t h2off  = ((wt2off + (size_t)w2Elems * 2 + 511) / 512) * 512;
  size_t need   = h2off + (size_t)Btot * 832 * 2;

  if (ws_size >= need){
    u16* Wb  = (u16*)((char*)d_ws + 256);
    u16* Wt  = (u16*)((char*)d_ws + wtoff);
    u16* Wt2 = (u16*)((char*)d_ws + wt2off);
    u16* h2g = (u16*)((char*)d_ws + h2off);
    hipLaunchKernelGGL(convert_kernel, dim3(38, 4), dim3(256), 0, stream, T, fl, Wb, O);
    hipLaunchKernelGGL(transpose_kernel, dim3(14, 4), dim3(256), 0, stream, Wb, O, Wt, TF);
    hipLaunchKernelGGL(transpose2_kernel, dim3(12, 8), dim3(256), 0, stream, Wb, O, Wt2, F2);
    hipLaunchKernelGGL(k1m, dim3((unsigned)((Btot + 7) / 8)), dim3(512), 0, stream,
                       T, fl, Wb, O, Wt2, F2, h2g, Btot);
    hipLaunchKernelGGL(k2m, dim3((unsigned)((Btot + 15) / 16)), dim3(512), 0, stream,
                       Wb, O, Wt, TF, h2g, (float*)d_out, Btot);
  } else {
    hipLaunchKernelGGL(actor_v2, dim3((unsigned)((Btot + RR - 1) / RR)), dim3(TPB), 0, stream,
                       T, fl, (float*)d_out, Btot);
  }
}

// Round 17
// 314.540 us; speedup vs baseline: 1.0194x; 1.0194x over previous
//
#include <hip/hip_runtime.h>

typedef unsigned short u16;
typedef unsigned int   u32;

#define NIN 40

struct PtrTab { const void* p[NIN]; int n[NIN]; };
struct OffsT  { int o[38]; };
struct TOffs  { int o[14]; };
struct TOffs2 { int o[12]; };

typedef __attribute__((ext_vector_type(8))) short bf16x8;
typedef __attribute__((ext_vector_type(4))) float f32x4;
#define MFMA16(a,b,c) __builtin_amdgcn_mfma_f32_16x16x32_bf16(a,b,c,0,0,0)
// LDS-only barrier: qv visibility without draining the in-flight weight stage
#define LGKM_BARRIER() asm volatile("s_waitcnt lgkmcnt(0)\n\ts_barrier" ::: "memory")

__device__ __forceinline__ float bf2f(u16 u){ union{u32 i; float f;} z; z.i = ((u32)u) << 16; return z.f; }
__device__ __forceinline__ u16 f2bf(float f){ union{float f; u32 i;} z; z.f = f; u32 u = z.i; return (u16)((u + 0x7fffu + ((u >> 16) & 1u)) >> 16); }
__device__ __forceinline__ float eluf(float x){ return x > 0.f ? x : (__expf(x) - 1.f); }
__device__ __forceinline__ float sigmf(float x){ return 1.f / (1.f + __expf(-x)); }

__device__ __forceinline__ float ldv(const void* p, int i, bool BF){
  if (BF){ return bf2f(((const u16*)p)[i]); }
  return ((const float*)p)[i];
}
__device__ __forceinline__ void bf8(const u16* p, float* f){
  uint4 w = *(const uint4*)(const void*)p;
  union{u32 i; float v;} t;
  t.i = w.x << 16; f[0] = t.v;  t.i = w.x & 0xffff0000u; f[1] = t.v;
  t.i = w.y << 16; f[2] = t.v;  t.i = w.y & 0xffff0000u; f[3] = t.v;
  t.i = w.z << 16; f[4] = t.v;  t.i = w.z & 0xffff0000u; f[5] = t.v;
  t.i = w.w << 16; f[6] = t.v;  t.i = w.w & 0xffff0000u; f[7] = t.v;
}
__device__ __forceinline__ void ld8(const void* p, int i, bool BF, float* f){
  if (BF){ bf8((const u16*)p + i, f); }
  else {
    const float4* q = (const float4*)(const void*)((const float*)p + i);
    float4 a = q[0], b = q[1];
    f[0]=a.x; f[1]=a.y; f[2]=a.z; f[3]=a.w; f[4]=b.x; f[5]=b.y; f[6]=b.z; f[7]=b.w;
  }
}
__device__ __forceinline__ void st8bf(u16* p, const float* f){
  u16 tmp[8];
  #pragma unroll
  for (int jj = 0; jj < 8; ++jj) tmp[jj] = f2bf(f[jj]);
  *(uint4*)(void*)p = *(const uint4*)(const void*)tmp;
}

// ---- swizzled LDS helpers (256B row stride, byte ^= (row&7)<<4) ----
__device__ __forceinline__ void st8_swz(u16* base, int row, int k0, const float* f){
  int byte = (row*256 + k0*2) ^ ((row & 7) << 4);
  u16 tmp[8];
  #pragma unroll
  for (int jj = 0; jj < 8; ++jj) tmp[jj] = f2bf(f[jj]);
  *(uint4*)((char*)base + byte) = *(const uint4*)(const void*)tmp;
}
__device__ __forceinline__ void st1_swz(u16* base, int row, int col, float v){
  int byte = (row*256 + col*2) ^ ((row & 7) << 4);
  *(u16*)((char*)base + byte) = f2bf(v);
}
__device__ __forceinline__ bf16x8 ldfrag(const u16* base, int row, int k0){
  int byte = (row*256 + k0*2) ^ ((row & 7) << 4);
  return *(const bf16x8*)((const char*)base + byte);
}
// 512B-stride variants (K=256 tiles in k2m)
__device__ __forceinline__ bf16x8 ldfrag5(const u16* base, int row, int k0){
  int byte = (row*512 + k0*2) ^ ((row & 7) << 4);
  return *(const bf16x8*)((const char*)base + byte);
}
__device__ __forceinline__ void st1_5(u16* base, int row, int col, float v){
  int byte = (row*512 + col*2) ^ ((row & 7) << 4);
  *(u16*)((char*)base + byte) = f2bf(v);
}

// async global->LDS, 16B per lane; LDS dest = wave-uniform base + lane*16
__device__ __forceinline__ void gl16(const u16* g, u16* l){
  __builtin_amdgcn_global_load_lds((const __attribute__((address_space(1))) void*)g,
                                   (__attribute__((address_space(3))) void*)l, 16, 0, 0);
}

__device__ __forceinline__ int nbr_cnt(int n){ return n == 0 ? 4 : (n <= 8 ? 2 : 1); }
__device__ __forceinline__ int nbr_of(int n, int e){
  if (n == 0) return 1 + e;
  if (n <= 4) return e == 0 ? 0 : n + 4;
  if (n <= 8) return e == 0 ? n - 4 : n + 4;
  return n - 4;
}
__device__ __forceinline__ int prowf(int n, int r){
  return n == 0 ? 96 + r : n <= 4 ? (n-1)*8 + r : n <= 8 ? 32 + (n-5)*8 + r : 64 + (n-9)*8 + r;
}

// ---- per-input dtype probe (verified R6-R16): 1 = bf16, 0 = f32 ----
__global__ __launch_bounds__(256) void probe_kernel(PtrTab T, int* fl){
  const int i = blockIdx.x;
  __shared__ int cnt;
  if (threadIdx.x == 0) cnt = 0;
  __syncthreads();
  int S = T.n[i]; if (S > 8192) S = 8192;
  const u16* p = (const u16*)T.p[i];
  int c = 0;
  for (int w = threadIdx.x; w < S; w += 256){
    u32 e = ((u32)p[w] >> 7) & 0xFFu;
    c += (e != 0u && (e < 96u || e > 159u)) ? 1 : 0;
  }
  atomicAdd(&cnt, c);
  __syncthreads();
  if (threadIdx.x == 0) fl[i] = (cnt > (S >> 4)) ? 0 : 1;
}

__global__ __launch_bounds__(256) void convert_kernel(PtrTab T, const int* fl, u16* dst, OffsT O){
  int s = blockIdx.x + 2;
  int j = (s >= 3 && (s & 1)) ? s - 1 : s;
  bool BF = fl[j] != 0;
  const void* src = T.p[s];
  u16* d = dst + O.o[s - 2];
  int n = T.n[s];
  for (int i = blockIdx.y * 256 + threadIdx.x; i < n; i += 1024)
    d[i] = BF ? ((const u16*)src)[i] : f2bf(((const float*)src)[i]);
}

// plain transpose (k2m mats): W[k][c] -> Wt[c][k]
__global__ __launch_bounds__(256) void transpose_kernel(const u16* Wb, OffsT O, u16* Wt, TOffs TF){
  static const int srcI[14] = {2,6,10,14, 16,18,20,22, 24,26,28,30, 32,34};
  static const int KK[14]   = {128,128,128,128, 128,128,128,128, 128,128,128,128, 256,256};
  static const int NNm[14]  = {64,64,64,64, 128,128,128,128, 64,64,64,64, 256,128};
  int m = blockIdx.x;
  int K = KK[m], N = NNm[m];
  const u16* src = Wb + O.o[srcI[m]];
  u16* dst = Wt + TF.o[m];
  int tot = K * N;
  for (int i = blockIdx.y * 256 + threadIdx.x; i < tot; i += 1024){
    int k = i / N, c = i % N;
    dst[c * K + k] = src[i];
  }
}

// pre-swizzled chunk-linear weights for k1m's global_load_lds staging.
__global__ __launch_bounds__(256) void transpose2_kernel(const u16* Wb, OffsT O, u16* Wt2, TOffs2 F2){
  static const int srcI[12] = {2,6,10,14, 16,18,20,22, 24,26,28,30};
  static const int NN2[12]  = {64,64,64,64, 128,128,128,128, 64,64,64,64};
  int m = blockIdx.x;
  int N = NN2[m];
  const u16* src = Wb + O.o[srcI[m]];
  u16* dst = Wt2 + F2.o[m];
  int tot = 128 * N;
  for (int i = blockIdx.y * 256 + threadIdx.x; i < tot; i += 2048){
    int ch = i >> 11;
    int x2 = (i & 2047) * 2;
    int c  = x2 >> 8;
    int sb = x2 ^ ((c & 7) << 4);
    int scol = ch*16 + (sb >> 8);
    int sk   = (sb & 255) >> 1;
    dst[i] = src[sk * N + scol];
  }
}

// ========== K1-MFMA v6: lgkm-only mid-phase barrier + packed qv (u32) ==========
__global__ __launch_bounds__(512, 4) void k1m(PtrTab T, const int* flg, const u16* Wb, OffsT O,
                                              const u16* Wt2, TOffs2 F2, u16* h2g, int Btot){
  __shared__ __attribute__((aligned(16))) u16 hidB[112*128];  // hidden/h1; rows 0..63 alias wlB (phaseB, gn2)
  __shared__ __attribute__((aligned(16))) u16 xs  [112*128];  // x/h2;     rows 0..63 alias wlB (gn1)
  __shared__ __attribute__((aligned(16))) u16 wl  [4*16*128]; // weight buffer A
  __shared__ __attribute__((aligned(16))) u32 qv32[104*19];   // packed (v<<16)|q  7904B
  float* obs_s = (float*)qv32;   // 3552B alias, dead after phase A

  const int tid = threadIdx.x, lane = tid & 63, wid = tid >> 6;
  const int lrow = lane & 15, lkg = lane >> 4;
  const int b0 = blockIdx.x * 8;
  const bool BFobs = flg[0] != 0, BFlat = flg[1] != 0;

  // early pre-stage: phase-B chunk 0 -> wlA (flies under setup + phase A)
  {
    #pragma unroll
    for (int j = 0; j < 2; ++j){
      int u = tid + j*512, m = u >> 8, um = u & 255;
      gl16(Wt2 + F2.o[m] + um*8, wl + m*2048 + (um & 192)*8);
    }
  }
  {
    uint4 z = {0,0,0,0};
    uint4* ph = (uint4*)((char*)hidB + 104*256);
    uint4* px = (uint4*)((char*)xs   + 104*256);
    for (int u = tid; u < 128; u += 512){ ph[u] = z; px[u] = z; }
  }
  for (int u = tid; u < 8*111; u += 512){
    int r = u / 111, c = u % 111;
    int br = b0 + r; if (br >= Btot) br = Btot - 1;
    obs_s[r*111 + c] = ldv(T.p[0], br*111 + c, BFobs);
  }
  __syncthreads();

  // phase A: node-MLP hidden (elu) -> hidB at prow (type-ordered)
  for (int u = tid; u < 13*128; u += 512){
    int n = u >> 7, rem = u & 127, r = rem >> 4, h0 = (rem & 15) << 3;
    int ty  = (n == 0) ? 0 : (n <= 4) ? 1 : (n <= 8) ? 2 : 3;
    int off = (n == 0) ? 0 : (ty == 1) ? 15 + 24*(n-1)
             : (ty == 2) ? 15 + 24*(n-5) + 8 : 15 + 24*(n-9) + 16;
    int K = (n == 0) ? 15 : 8;
    const u16* w1 = Wb + O.o[4*ty];
    float acc8[8]; bf8(Wb + O.o[4*ty+1] + h0, acc8);
    for (int k = 0; k < K; ++k){
      float xv = obs_s[r*111 + off + k];
      float wf[8]; bf8(w1 + k*128 + h0, wf);
      #pragma unroll
      for (int jj = 0; jj < 8; ++jj) acc8[jj] = fmaf(xv, wf[jj], acc8[jj]);
    }
    #pragma unroll
    for (int jj = 0; jj < 8; ++jj) acc8[jj] = eluf(acc8[jj]);
    st8_swz(hidB, prowf(n, r), h0, acc8);
  }
  for (int u = tid; u < 13*64; u += 512){
    int n = u >> 6, rem = u & 63, r = rem >> 3, j0 = (rem & 7) << 3;
    int br = b0 + r; if (br >= Btot) br = Btot - 1;
    float lv[8]; ld8(T.p[1], (br*13 + n)*64 + j0, BFlat, lv);
    st8_swz(xs, n*8 + r, 64 + j0, lv);
  }
  __syncthreads();

  bf16x8 axf[4];

  // ---- phase B: x cols 0..63 = hidden @ w2[type]; wlB aliases hidB rows 0..63 ----
  if (wid < 7){
    #pragma unroll
    for (int kk = 0; kk < 4; ++kk) axf[kk] = ldfrag(hidB, wid*16 + lrow, kk*32 + lkg*8);
  }
  __syncthreads();   // axf(hidB) complete before ch1 stage clobbers hidB alias
  for (int ch = 0; ch < 4; ++ch){
    // stage next FIRST (other buffer): ch<3 -> phaseB ch+1; ch==3 -> gn1 chunk0 -> wlA
    #pragma unroll
    for (int j = 0; j < 2; ++j){
      int u = tid + j*512, m = u >> 8, um = u & 255;
      const u16* g; u16* dst;
      if (ch < 3){
        g = Wt2 + F2.o[m] + (ch+1)*2048 + um*8;
        dst = (((ch+1) & 1) ? hidB : wl) + m*2048 + (um & 192)*8;
      } else {
        g = Wt2 + F2.o[4+m] + um*8;
        dst = wl + m*2048 + (um & 192)*8;
      }
      gl16(g, dst);
    }
    const u16* wb = (ch & 1) ? hidB : wl;
    if (wid < 7){
      int t = wid;
      int tyt = t < 2 ? 1 : t < 4 ? 2 : t < 6 ? 3 : 0;
      f32x4 d = {0.f,0.f,0.f,0.f};
      #pragma unroll
      for (int kk = 0; kk < 4; ++kk){
        bf16x8 b = ldfrag(wb + tyt*2048, lrow, kk*32 + lkg*8);
        d = MFMA16(axf[kk], b, d);
      }
      int c2 = ch*16 + lrow;
      float bb = bf2f(Wb[O.o[4*tyt+3] + c2]);
      #pragma unroll
      for (int i = 0; i < 4; ++i){
        int prow = t*16 + lkg*4 + i;
        if (prow < 104){
          int n = prow < 32 ? 1 + (prow >> 3) : prow < 64 ? 5 + ((prow-32) >> 3)
                : prow < 96 ? 9 + ((prow-64) >> 3) : 0;
          st1_swz(xs, n*8 + (prow & 7), c2, d[i] + bb);
        }
      }
    }
    __syncthreads();   // drains stage (aged); buffer rotation safe
  }

  // ---- gn1: A = x (regs); wlB aliases xs rows 0..63; h1 -> hidB ----
  if (wid < 7){
    #pragma unroll
    for (int kk = 0; kk < 4; ++kk) axf[kk] = ldfrag(xs, wid*16 + lrow, kk*32 + lkg*8);
  }
  __syncthreads();   // axf(xs) complete before ch1 stage clobbers xs alias
  {
    const u16* bk = Wb + O.o[17]; const u16* bq = Wb + O.o[19];
    const u16* bv = Wb + O.o[21]; const u16* bs = Wb + O.o[23];
    for (int ch = 0; ch < 8; ++ch){
      // stage next FIRST: ch<7 -> gn1 ch+1; ch==7 -> gn2 chunk0 -> wlA
      #pragma unroll
      for (int j = 0; j < 2; ++j){
        int u = tid + j*512, m = u >> 8, um = u & 255;
        const u16* g; u16* dst;
        if (ch < 7){
          g = Wt2 + F2.o[4+m] + (ch+1)*2048 + um*8;
          dst = (((ch+1) & 1) ? xs : wl) + m*2048 + (um & 192)*8;
        } else {
          g = Wt2 + F2.o[8+m] + um*8;
          dst = wl + m*2048 + (um & 192)*8;
        }
        gl16(g, dst);
      }
      const u16* wb = (ch & 1) ? xs : wl;
      int c0 = ch * 16;
      f32x4 kacc = {0.f,0.f,0.f,0.f}, sacc = {0.f,0.f,0.f,0.f};
      f32x4 qsv  = {0.f,0.f,0.f,0.f};
      if (wid < 7){
        int t = wid;
        #pragma unroll
        for (int m = 0; m < 4; ++m){
          f32x4 d = {0.f,0.f,0.f,0.f};
          #pragma unroll
          for (int kk = 0; kk < 4; ++kk){
            bf16x8 b = ldfrag(wb + m*2048, lrow, kk*32 + lkg*8);
            d = MFMA16(axf[kk], b, d);
          }
          if (m == 0) kacc = d;
          else if (m == 1) qsv = d;
          else if (m == 3) sacc = d;
          else {   // m == 2: pack (v<<16)|q, single b32 write
            #pragma unroll
            for (int i = 0; i < 4; ++i){
              int gr = t*16 + lkg*4 + i;
              if (gr < 104){
                u32 pk = ((u32)f2bf(d[i]) << 16) | (u32)f2bf(qsv[i]);
                qv32[gr*19 + lrow] = pk;
              }
            }
          }
        }
      }
      LGKM_BARRIER();    // qv visibility only; weight stage stays in flight
      if (wid < 7){
        int t = wid, c = c0 + lrow;
        float bkq = bf2f(bk[c]) + bf2f(bq[c]);
        float bvv = bf2f(bv[c]);
        float bss = bf2f(bs[c]);
        #pragma unroll
        for (int i = 0; i < 4; ++i){
          int gr = t*16 + lkg*4 + i;
          if (gr < 104){
            int n = gr >> 3, rr = gr & 7;
            float acc = sacc[i] + bss;
            float kk_ = kacc[i] + bkq;
            int cnt = nbr_cnt(n);
            for (int e = 0; e < cnt; ++e){
              int s = nbr_of(n, e);
              u32 pk = qv32[(s*8 + rr)*19 + lrow];
              float ql = bf2f((u16)(pk & 0xffffu));
              float vl = bf2f((u16)(pk >> 16));
              acc += sigmf(kk_ + ql) * (vl + bvv);
            }
            st1_swz(hidB, gr, c, eluf(acc));
          }
        }
      }
      __syncthreads();   // qv reuse protection; drains (aged) stage
    }
  }

  // ---- gn2: A = h1 (regs); wlB aliases hidB rows 0..63; h2 -> xs (plain) ----
  if (wid < 7){
    #pragma unroll
    for (int kk = 0; kk < 4; ++kk) axf[kk] = ldfrag(hidB, wid*16 + lrow, kk*32 + lkg*8);
  }
  __syncthreads();   // axf(h1) complete before ch1 stage clobbers hidB alias
  {
    const u16* bk = Wb + O.o[25]; const u16* bq = Wb + O.o[27];
    const u16* bv = Wb + O.o[29]; const u16* bs = Wb + O.o[31];
    for (int ch = 0; ch < 4; ++ch){
      if (ch < 3){
        #pragma unroll
        for (int j = 0; j < 2; ++j){
          int u = tid + j*512, m = u >> 8, um = u & 255;
          u16* dst = (((ch+1) & 1) ? hidB : wl) + m*2048 + (um & 192)*8;
          gl16(Wt2 + F2.o[8+m] + (ch+1)*2048 + um*8, dst);
        }
      }
      const u16* wb = (ch & 1) ? hidB : wl;
      int c0 = ch * 16;
      f32x4 kacc = {0.f,0.f,0.f,0.f}, sacc = {0.f,0.f,0.f,0.f};
      f32x4 qsv  = {0.f,0.f,0.f,0.f};
      if (wid < 7){
        int t = wid;
        #pragma unroll
        for (int m = 0; m < 4; ++m){
          f32x4 d = {0.f,0.f,0.f,0.f};
          #pragma unroll
          for (int kk = 0; kk < 4; ++kk){
            bf16x8 b = ldfrag(wb + m*2048, lrow, kk*32 + lkg*8);
            d = MFMA16(axf[kk], b, d);
          }
          if (m == 0) kacc = d;
          else if (m == 1) qsv = d;
          else if (m == 3) sacc = d;
          else {
            #pragma unroll
            for (int i = 0; i < 4; ++i){
              int gr = t*16 + lkg*4 + i;
              if (gr < 104){
                u32 pk = ((u32)f2bf(d[i]) << 16) | (u32)f2bf(qsv[i]);
                qv32[gr*19 + lrow] = pk;
              }
            }
          }
        }
      }
      LGKM_BARRIER();
      if (wid < 7){
        int t = wid, c = c0 + lrow;
        float bkq = bf2f(bk[c]) + bf2f(bq[c]);
        float bvv = bf2f(bv[c]);
        float bss = bf2f(bs[c]);
        #pragma unroll
        for (int i = 0; i < 4; ++i){
          int gr = t*16 + lkg*4 + i;
          if (gr < 104){
            int n = gr >> 3, rr = gr & 7;
            float acc = sacc[i] + bss;
            float kk_ = kacc[i] + bkq;
            int cnt = nbr_cnt(n);
            for (int e = 0; e < cnt; ++e){
              int s = nbr_of(n, e);
              u32 pk = qv32[(s*8 + rr)*19 + lrow];
              float ql = bf2f((u16)(pk & 0xffffu));
              float vl = bf2f((u16)(pk >> 16));
              acc += sigmf(kk_ + ql) * (vl + bvv);
            }
            xs[gr*128 + c] = f2bf(acc);
          }
        }
      }
      __syncthreads();
    }
  }

  for (int u = tid; u < 104*8; u += 512){
    int gr = u >> 3, j0 = (u & 7) << 3;
    int n = gr >> 3, rr = gr & 7;
    if (b0 + rr < Btot)
      *(uint4*)(h2g + ((b0 + rr)*13 + n)*64 + j0) = *(const uint4*)(xs + gr*128 + j0);
  }
}

// ========== K2-MFMA (proven R10): leg MLP, 64 instances/block ==========
__global__ __launch_bounds__(512) void k2m(const u16* Wb, OffsT O, const u16* Wt, TOffs TF,
                                           const u16* h2g, float* out, int Btot){
  __shared__ u16 lat [64*256];
  __shared__ u16 a1s [64*256];
  __shared__ u16 a2s [64*128];
  __shared__ u16 wbuf[2][32*256];

  const int tid  = threadIdx.x;
  const int lane = tid & 63;
  const int wid  = tid >> 6;
  const int lrow = lane & 15;
  const int lkg  = lane >> 4;
  const int r0   = blockIdx.x * 16;
  const int mt   = wid >> 1, cb = wid & 1;

  for (int u = tid; u < 64*32; u += 512){
    int inst = u >> 5, k0 = (u & 31) << 3;
    int r = inst >> 2, g = inst & 3;
    int br = r0 + r; if (br >= Btot) br = Btot - 1;
    int seg = k0 >> 6, f = k0 & 63;
    int node = (seg == 0) ? 0 : (seg - 1)*4 + 1 + g;
    uint4 v = *(const uint4*)(h2g + (br*13 + node)*64 + f);
    *(uint4*)((char*)lat + ((inst*512 + k0*2) ^ ((inst&7)<<4))) = v;
  }
  const u16* w1t = Wt + TF.o[12];
  const u16* b1  = Wb + O.o[33];
  for (int u = tid; u < 1024; u += 512){
    int c = u >> 5, kg = (u & 31) << 3;
    uint4 v = *(const uint4*)(w1t + c*256 + kg);
    *(uint4*)((char*)wbuf[0] + ((c*512 + kg*2) ^ ((c&7)<<4))) = v;
  }
  __syncthreads();

  for (int ch = 0; ch < 8; ++ch){
    if (ch < 7){
      for (int u = tid; u < 1024; u += 512){
        int c = u >> 5, kg = (u & 31) << 3;
        uint4 v = *(const uint4*)(w1t + ((ch+1)*32 + c)*256 + kg);
        *(uint4*)((char*)wbuf[(ch+1)&1] + ((c*512 + kg*2) ^ ((c&7)<<4))) = v;
      }
    }
    const u16* wb = wbuf[ch&1];
    f32x4 d = {0.f,0.f,0.f,0.f};
    #pragma unroll
    for (int kk = 0; kk < 8; ++kk){
      bf16x8 a = ldfrag5(lat, mt*16 + lrow, kk*32 + lkg*8);
      bf16x8 b = ldfrag5(wb,  cb*16 + lrow, kk*32 + lkg*8);
      d = MFMA16(a, b, d);
    }
    int col = ch*32 + cb*16 + lrow;
    float bvv = bf2f(b1[col]);
    #pragma unroll
    for (int i = 0; i < 4; ++i)
      st1_5(a1s, mt*16 + lkg*4 + i, col, eluf(d[i] + bvv));
    __syncthreads();
  }

  const u16* w2t = Wt + TF.o[13];
  const u16* b2  = Wb + O.o[35];
  for (int u = tid; u < 1024; u += 512){
    int c = u >> 5, kg = (u & 31) << 3;
    uint4 v = *(const uint4*)(w2t + c*256 + kg);
    *(uint4*)((char*)wbuf[0] + ((c*512 + kg*2) ^ ((c&7)<<4))) = v;
  }
  __syncthreads();
  for (int ch = 0; ch < 4; ++ch){
    if (ch < 3){
      for (int u = tid; u < 1024; u += 512){
        int c = u >> 5, kg = (u & 31) << 3;
        uint4 v = *(const uint4*)(w2t + ((ch+1)*32 + c)*256 + kg);
        *(uint4*)((char*)wbuf[(ch+1)&1] + ((c*512 + kg*2) ^ ((c&7)<<4))) = v;
      }
    }
    const u16* wb = wbuf[ch&1];
    f32x4 d = {0.f,0.f,0.f,0.f};
    #pragma unroll
    for (int kk = 0; kk < 8; ++kk){
      bf16x8 a = ldfrag5(a1s, mt*16 + lrow, kk*32 + lkg*8);
      bf16x8 b = ldfrag5(wb,  cb*16 + lrow, kk*32 + lkg*8);
      d = MFMA16(a, b, d);
    }
    int col = ch*32 + cb*16 + lrow;
    float bvv = bf2f(b2[col]);
    #pragma unroll
    for (int i = 0; i < 4; ++i)
      st1_swz(a2s, mt*16 + lkg*4 + i, col, eluf(d[i] + bvv));
    __syncthreads();
  }

  if (tid < 64*3){
    const u16* w3 = Wb + O.o[36], *b3 = Wb + O.o[37];
    int inst = tid / 3, c = tid % 3;
    int r = inst >> 2, g = inst & 3;
    float acc = bf2f(b3[c]);
    for (int k0 = 0; k0 < 128; k0 += 8){
      const u16* ap = (const u16*)((const char*)a2s + ((inst*256 + k0*2) ^ ((inst&7)<<4)));
      float av[8]; bf8(ap, av);
      #pragma unroll
      for (int jj = 0; jj < 8; ++jj) acc = fmaf(av[jj], bf2f(w3[(k0+jj)*3 + c]), acc);
    }
    if (r0 + r < Btot) out[(r0 + r)*12 + g*3 + c] = acc;
  }
}

// ================= fallback: R7 monolithic kernel (proven) =================
#define TPB 512
#define RR  6
__global__ __launch_bounds__(TPB) void actor_v2(PtrTab T, const int* flg, float* out, int Btot){
  __shared__ float A [RR][13][132];
  __shared__ float Bf[RR][13][132];
  __shared__ u16   Cq[3][RR][13][128];
  __shared__ float obs_s[RR][111];
  __shared__ int   fls[NIN];

  const int tid = threadIdx.x;
  const int b0  = blockIdx.x * RR;

  if (tid < NIN){ int j = (tid >= 3 && (tid & 1)) ? tid - 1 : tid; fls[tid] = flg[j]; }
  __syncthreads();
  const bool BFobs = fls[0] != 0, BFlat = fls[1] != 0;

  for (int u = tid; u < RR * 111; u += TPB){
    int r = u / 111, c = u % 111;
    int br = b0 + r; if (br >= Btot) br = Btot - 1;
    obs_s[r][c] = ldv(T.p[0], br * 111 + c, BFobs);
  }
  __syncthreads();

  for (int u = tid; u < RR * 13 * 16; u += TPB){
    int r = u / 208, rem = u % 208, n = rem >> 4, h0 = (rem & 15) << 3;
    int ty  = (n == 0) ? 0 : (n <= 4) ? 1 : (n <= 8) ? 2 : 3;
    int off = (n == 0) ? 0 : (ty == 1) ? 15 + 24 * (n - 1)
             : (ty == 2) ? 15 + 24 * (n - 5) + 8 : 15 + 24 * (n - 9) + 16;
    int K = (n == 0) ? 15 : 8;
    const void* w1 = T.p[2 + 4 * ty];
    bool bw = fls[2 + 4 * ty] != 0, bb = fls[3 + 4 * ty] != 0;
    float acc8[8]; ld8(T.p[3 + 4 * ty], h0, bb, acc8);
    for (int k = 0; k < K; ++k){
      float xv = obs_s[r][off + k];
      float wf[8]; ld8(w1, k * 128 + h0, bw, wf);
      #pragma unroll
      for (int jj = 0; jj < 8; ++jj) acc8[jj] = fmaf(xv, wf[jj], acc8[jj]);
    }
    #pragma unroll
    for (int jj = 0; jj < 8; ++jj) Bf[r][n][h0 + jj] = eluf(acc8[jj]);
  }
  __syncthreads();

  for (int u = tid; u < 13 * 8; u += TPB){
    int n = u >> 3, o0 = (u & 7) << 3;
    int ty = (n == 0) ? 0 : (n <= 4) ? 1 : (n <= 8) ? 2 : 3;
    const void* w2 = T.p[4 + 4 * ty];
    bool bw = fls[4 + 4 * ty] != 0, bb = fls[5 + 4 * ty] != 0;
    float bv[8]; ld8(T.p[5 + 4 * ty], o0, bb, bv);
    float acc[RR][8];
    #pragma unroll
    for (int r = 0; r < RR; ++r)
      #pragma unroll
      for (int jj = 0; jj < 8; ++jj) acc[r][jj] = bv[jj];
    #pragma unroll 4
    for (int k = 0; k < 128; ++k){
      float wf[8]; ld8(w2, k * 64 + o0, bw, wf);
      #pragma unroll
      for (int r = 0; r < RR; ++r){
        float xv = Bf[r][n][k];
        #pragma unroll
        for (int jj = 0; jj < 8; ++jj) acc[r][jj] = fmaf(xv, wf[jj], acc[r][jj]);
      }
    }
    #pragma unroll
    for (int r = 0; r < RR; ++r)
      #pragma unroll
      for (int jj = 0; jj < 8; ++jj) A[r][n][o0 + jj] = acc[r][jj];
  }
  for (int u = tid; u < RR * 13 * 8; u += TPB){
    int r = u / 104, rem = u % 104, n = rem >> 3, j0 = (rem & 7) << 3;
    int br = b0 + r; if (br >= Btot) br = Btot - 1;
    float lv[8]; ld8(T.p[1], (br * 13 + n) * 64 + j0, BFlat, lv);
    #pragma unroll
    for (int jj = 0; jj < 8; ++jj) A[r][n][64 + j0 + jj] = lv[jj];
  }
  __syncthreads();

  for (int u = tid; u < 4 * 13 * 16; u += TPB){
    int mat = u / 208, rem = u % 208, n = rem >> 4, j0 = (rem & 15) << 3;
    const void* W = T.p[18 + 2 * mat];
    bool bw = fls[18 + 2 * mat] != 0, bb = fls[19 + 2 * mat] != 0;
    float bv[8]; ld8(T.p[19 + 2 * mat], j0, bb, bv);
    float acc[RR][8];
    #pragma unroll
    for (int r = 0; r < RR; ++r)
      #pragma unroll
      for (int jj = 0; jj < 8; ++jj) acc[r][jj] = bv[jj];
    #pragma unroll 4
    for (int k = 0; k < 128; ++k){
      float wf[8]; ld8(W, k * 128 + j0, bw, wf);
      #pragma unroll
      for (int r = 0; r < RR; ++r){
        float xv = A[r][n][k];
        #pragma unroll
        for (int jj = 0; jj < 8; ++jj) acc[r][jj] = fmaf(xv, wf[jj], acc[r][jj]);
      }
    }
    if (mat < 3){
      #pragma unroll
      for (int r = 0; r < RR; ++r) st8bf(&Cq[mat][r][n][j0], acc[r]);
    } else {
      #pragma unroll
      for (int r = 0; r < RR; ++r)
        #pragma unroll
        for (int jj = 0; jj < 8; ++jj) Bf[r][n][j0 + jj] = acc[r][jj];
    }
  }
  __syncthreads();

  for (int u = tid; u < RR * 13 * 16; u += TPB){
    int r = u / 208, rem = u % 208, n = rem >> 4, j0 = (rem & 15) << 3;
    float acc8[8];
    #pragma unroll
    for (int jj = 0; jj < 8; ++jj) acc8[jj] = Bf[r][n][j0 + jj];
    float k8[8]; bf8(&Cq[0][r][n][j0], k8);
    int cnt = nbr_cnt(n);
    for (int e = 0; e < cnt; ++e){
      int s = nbr_of(n, e);
      float q8[8], v8[8];
      bf8(&Cq[1][r][s][j0], q8);
      bf8(&Cq[2][r][s][j0], v8);
      #pragma unroll
      for (int jj = 0; jj < 8; ++jj) acc8[jj] = fmaf(sigmf(k8[jj] + q8[jj]), v8[jj], acc8[jj]);
    }
    #pragma unroll
    for (int jj = 0; jj < 8; ++jj) Bf[r][n][j0 + jj] = eluf(acc8[jj]);
  }
  __syncthreads();

  for (int u = tid; u < 4 * 13 * 8; u += TPB){
    int mat = u / 104, rem = u % 104, n = rem >> 3, j0 = (rem & 7) << 3;
    const void* W = T.p[26 + 2 * mat];
    bool bw = fls[26 + 2 * mat] != 0, bb = fls[27 + 2 * mat] != 0;
    float bv[8]; ld8(T.p[27 + 2 * mat], j0, bb, bv);
    float acc[RR][8];
    #pragma unroll
    for (int r = 0; r < RR; ++r)
      #pragma unroll
      for (int jj = 0; jj < 8; ++jj) acc[r][jj] = bv[jj];
    #pragma unroll 4
    for (int k = 0; k < 128; ++k){
      float wf[8]; ld8(W, k * 64 + j0, bw, wf);
      #pragma unroll
      for (int r = 0; r < RR; ++r){
        float xv = Bf[r][n][k];
        #pragma unroll
        for (int jj = 0; jj < 8; ++jj) acc[r][jj] = fmaf(xv, wf[jj], acc[r][jj]);
      }
    }
    if (mat < 3){
      #pragma unroll
      for (int r = 0; r < RR; ++r) st8bf(&Cq[mat][r][n][j0], acc[r]);
    } else {
      #pragma unroll
      for (int r = 0; r < RR; ++r)
        #pragma unroll
        for (int jj = 0; jj < 8; ++jj) A[r][n][j0 + jj] = acc[r][jj];
    }
  }
  __syncthreads();

  for (int u = tid; u < RR * 13 * 8; u += TPB){
    int r = u / 104, rem = u % 104, n = rem >> 3, j0 = (rem & 7) << 3;
    float acc8[8];
    #pragma unroll
    for (int jj = 0; jj < 8; ++jj) acc8[jj] = A[r][n][j0 + jj];
    float k8[8]; bf8(&Cq[0][r][n][j0], k8);
    int cnt = nbr_cnt(n);
    for (int e = 0; e < cnt; ++e){
      int s = nbr_of(n, e);
      float q8[8], v8[8];
      bf8(&Cq[1][r][s][j0], q8);
      bf8(&Cq[2][r][s][j0], v8);
      #pragma unroll
      for (int jj = 0; jj < 8; ++jj) acc8[jj] = fmaf(sigmf(k8[jj] + q8[jj]), v8[jj], acc8[jj]);
    }
    #pragma unroll
    for (int jj = 0; jj < 8; ++jj) A[r][n][j0 + jj] = acc8[jj];
  }
  __syncthreads();

  float* a1f = (float*)&Cq[0][0][0][0];
  float* a2f = (float*)&Bf[0][0][0];
  {
    bool bw = fls[34] != 0, bb = fls[35] != 0;
    for (int u = tid; u < 6 * 32; u += TPB){
      int iq = u >> 5, j0 = (u & 31) << 3;
      float bv[8]; ld8(T.p[35], j0, bb, bv);
      float acc[4][8];
      #pragma unroll
      for (int t = 0; t < 4; ++t)
        #pragma unroll
        for (int jj = 0; jj < 8; ++jj) acc[t][jj] = bv[jj];
      #pragma unroll 2
      for (int k = 0; k < 256; ++k){
        float wf[8]; ld8(T.p[34], k * 256 + j0, bw, wf);
        int seg = k >> 6, f = k & 63;
        #pragma unroll
        for (int t = 0; t < 4; ++t){
          int inst = iq * 4 + t, r = inst >> 2, g = inst & 3;
          int node = (seg == 0) ? 0 : (seg - 1) * 4 + 1 + g;
          float xv = A[r][node][f];
          #pragma unroll
          for (int jj = 0; jj < 8; ++jj) acc[t][jj] = fmaf(xv, wf[jj], acc[t][jj]);
        }
      }
      #pragma unroll
      for (int t = 0; t < 4; ++t){
        int inst = iq * 4 + t;
        #pragma unroll
        for (int jj = 0; jj < 8; ++jj) a1f[inst * 256 + j0 + jj] = eluf(acc[t][jj]);
      }
    }
  }
  __syncthreads();
  {
    bool bw = fls[36] != 0, bb = fls[37] != 0;
    for (int u = tid; u < 6 * 16; u += TPB){
      int iq = u >> 4, j0 = (u & 15) << 3;
      float bv[8]; ld8(T.p[37], j0, bb, bv);
      float acc[4][8];
      #pragma unroll
      for (int t = 0; t < 4; ++t)
        #pragma unroll
        for (int jj = 0; jj < 8; ++jj) acc[t][jj] = bv[jj];
      #pragma unroll 2
      for (int k = 0; k < 256; ++k){
        float wf[8]; ld8(T.p[36], k * 128 + j0, bw, wf);
        #pragma unroll
        for (int t = 0; t < 4; ++t){
          float xv = a1f[(iq * 4 + t) * 256 + k];
          #pragma unroll
          for (int jj = 0; jj < 8; ++jj) acc[t][jj] = fmaf(xv, wf[jj], acc[t][jj]);
        }
      }
      #pragma unroll
      for (int t = 0; t < 4; ++t){
        int inst = iq * 4 + t;
        #pragma unroll
        for (int jj = 0; jj < 8; ++jj) a2f[inst * 128 + j0 + jj] = eluf(acc[t][jj]);
      }
    }
  }
  __syncthreads();
  if (tid < RR * 4 * 3){
    int inst = tid / 3, c = tid % 3;
    int r = inst >> 2, g = inst & 3;
    bool bw = fls[38] != 0, bb = fls[39] != 0;
    float acc = ldv(T.p[39], c, bb);
    for (int k = 0; k < 128; ++k) acc = fmaf(a2f[inst * 128 + k], ldv(T.p[38], k * 3 + c, bw), acc);
    if (b0 + r < Btot) out[(b0 + r) * 12 + g * 3 + c] = acc;
  }
}

extern "C" void kernel_launch(void* const* d_in, const int* in_sizes, int n_in,
                              void* d_out, int out_size, void* d_ws, size_t ws_size,
                              hipStream_t stream){
  (void)out_size;
  PtrTab T;
  for (int i = 0; i < NIN; ++i){
    T.p[i] = (i < n_in) ? d_in[i] : d_in[0];
    T.n[i] = (i < n_in) ? in_sizes[i] : 1;
  }
  int* fl = (int*)d_ws;
  hipLaunchKernelGGL(probe_kernel, dim3(NIN), dim3(256), 0, stream, T, fl);

  int Btot = T.n[0] / 111;

  OffsT O;
  size_t acc = 0;
  for (int s = 0; s < 38; ++s){
    O.o[s] = (int)acc;
    acc += ((size_t)T.n[s + 2] + 7) & ~(size_t)7;
  }
  static const int KK[14] = {128,128,128,128, 128,128,128,128, 128,128,128,128, 256,256};
  static const int NNm[14]= {64,64,64,64, 128,128,128,128, 64,64,64,64, 256,128};
  TOffs TF;
  int wtElems = 0;
  for (int m = 0; m < 14; ++m){ TF.o[m] = wtElems; wtElems += KK[m]*NNm[m]; }
  static const int NN2[12] = {64,64,64,64, 128,128,128,128, 64,64,64,64};
  TOffs2 F2;
  int w2Elems = 0;
  for (int m = 0; m < 12; ++m){ F2.o[m] = w2Elems; w2Elems += 128*NN2[m]; }

  size_t wtoff  = ((256 + acc * 2 + 511) / 512) * 512;
  size_t wt2off = ((wtoff + (size_t)wtElems * 2 + 511) / 512) * 512;
  size_t h2off  = ((wt2off + (size_t)w2Elems * 2 + 511) / 512) * 512;
  size_t need   = h2off + (size_t)Btot * 832 * 2;

  if (ws_size >= need){
    u16* Wb  = (u16*)((char*)d_ws + 256);
    u16* Wt  = (u16*)((char*)d_ws + wtoff);
    u16* Wt2 = (u16*)((char*)d_ws + wt2off);
    u16* h2g = (u16*)((char*)d_ws + h2off);
    hipLaunchKernelGGL(convert_kernel, dim3(38, 4), dim3(256), 0, stream, T, fl, Wb, O);
    hipLaunchKernelGGL(transpose_kernel, dim3(14, 4), dim3(256), 0, stream, Wb, O, Wt, TF);
    hipLaunchKernelGGL(transpose2_kernel, dim3(12, 8), dim3(256), 0, stream, Wb, O, Wt2, F2);
    hipLaunchKernelGGL(k1m, dim3((unsigned)((Btot + 7) / 8)), dim3(512), 0, stream,
                       T, fl, Wb, O, Wt2, F2, h2g, Btot);
    hipLaunchKernelGGL(k2m, dim3((unsigned)((Btot + 15) / 16)), dim3(512), 0, stream,
                       Wb, O, Wt, TF, h2g, (float*)d_out, Btot);
  } else {
    hipLaunchKernelGGL(actor_v2, dim3((unsigned)((Btot + RR - 1) / RR)), dim3(TPB), 0, stream,
                       T, fl, (float*)d_out, Btot);
  }
}